// Round 2
// baseline (145.989 us; speedup 1.0000x reference)
//
#include <hip/hip_runtime.h>
#include <hip/hip_bf16.h>
#include <stdint.h>

typedef _Float16 f16x8 __attribute__((ext_vector_type(8)));
typedef float f32x4 __attribute__((ext_vector_type(4)));

#define MFMA_16x16x32_F16 __builtin_amdgcn_mfma_f32_16x16x32_f16

// Problem constants
constexpr int Bc = 4, Sc = 4096, Dc = 1024, Hc = 16, DHc = 64, CH = 256, NCc = 16;

union U32H2 { uint32_t u; _Float16 h[2]; };
union FragU { f16x8 v; uint32_t u[4]; };

// One block handles half a problem: 128 q-rows x full 256 k-rows, DH=64.
// Layouts:
//  Qn LDS: [256 rows][8 chunks of 8 fp16], chunk XOR-swizzled by (row&7). 32 KB.
//  Vt LDS: [64 d-rows][32 chunks of 8 fp16 along k], chunk XOR-swizzled by (d&7). 32 KB.
//  Ostage: [128 rows][16 blocks of 4 f32], block XOR-swizzled by (row&15). 32 KB (union).
__global__ __launch_bounds__(512, 4) void block_attn_kernel(
    const float* __restrict__ hid, const float* __restrict__ mask,
    float* __restrict__ out)
{
    const int bc   = blockIdx.x;
    const int half = bc & 1;
    const int p    = bc >> 1;          // 0..1023
    const int b    = p >> 8;
    const int h    = (p >> 4) & 15;
    const int sc   = p & 15;

    const float* __restrict__ qb_g = hid + ((size_t)(b * Sc + sc * CH) * Dc + h * DHc);
    float*       __restrict__ ob_g = out + ((size_t)(b * Sc + sc * CH) * Dc + h * DHc);
    const float* __restrict__ mk   = mask + b * Sc + h * CH;

    __shared__ __align__(16) union {
        struct { unsigned char qn[256 * 128]; unsigned char vt[64 * 512]; } s;
        float ostage[128 * 64];
    } sm;

    const int t = threadIdx.x;

    // ---------------- Stage Q (=K=V) into LDS as fp16 (Qn row-major, Vt transposed) ----
    #pragma unroll
    for (int it = 0; it < 8; ++it) {
        int f = t + it * 512;          // 0..4095 float4 tiles
        int r = f >> 4;                // row 0..255
        int c = f & 15;                // float4 col 0..15 (d = 4c..4c+3)
        float4 v = *(const float4*)(qb_g + (size_t)r * Dc + c * 4);
        U32H2 p0, p1;
        p0.h[0] = (_Float16)v.x; p0.h[1] = (_Float16)v.y;
        p1.h[0] = (_Float16)v.z; p1.h[1] = (_Float16)v.w;
        uint2 pv; pv.x = p0.u; pv.y = p1.u;
        *(uint2*)(&sm.s.qn[r * 128 + (((c >> 1) ^ (r & 7)) * 16) + (c & 1) * 8]) = pv;
        _Float16 hv0 = (_Float16)v.x, hv1 = (_Float16)v.y, hv2 = (_Float16)v.z, hv3 = (_Float16)v.w;
        _Float16 hvs[4] = {hv0, hv1, hv2, hv3};
        #pragma unroll
        for (int j = 0; j < 4; ++j) {
            int d = 4 * c + j;
            *(_Float16*)(&sm.s.vt[d * 512 + (((r >> 3) ^ (d & 7)) * 16) + (r & 7) * 2]) = hvs[j];
        }
    }
    __syncthreads();

    // ---------------- Per-wave setup ----------------
    const int wv = t >> 6;             // wave 0..7
    const int l  = t & 63;
    const int q  = l & 15;             // this lane's q column (within wave's 16)
    const int g  = l >> 4;             // lane group 0..3
    const int lq = wv * 16 + q;        // local q row 0..127
    const int qrow = half * 128 + lq;  // global q row 0..255

    // Q B-fragments (col = q, k-dim = d), loop-invariant
    FragU bq0, bq1;
    bq0.v = *(const f16x8*)(&sm.s.qn[qrow * 128 + (((0 + g) ^ (qrow & 7)) * 16)]);
    bq1.v = *(const f16x8*)(&sm.s.qn[qrow * 128 + (((4 + g) ^ (qrow & 7)) * 16)]);

    // ---------------- S^T = K * Q^T  (16 tiles of 16k x 16q), k-dim = d = 64 ----------
    f32x4 sacc[16];
    #pragma unroll
    for (int kt = 0; kt < 16; ++kt) {
        int kr = kt * 16 + q;          // A-frag row = key index (lane&15 pattern)
        f16x8 a0 = *(const f16x8*)(&sm.s.qn[kr * 128 + (((0 + g) ^ (kr & 7)) * 16)]);
        f16x8 a1 = *(const f16x8*)(&sm.s.qn[kr * 128 + (((4 + g) ^ (kr & 7)) * 16)]);
        f32x4 acc = {0.f, 0.f, 0.f, 0.f};
        acc = MFMA_16x16x32_F16(a0, bq0.v, acc, 0, 0, 0);
        acc = MFMA_16x16x32_F16(a1, bq1.v, acc, 0, 0, 0);
        sacc[kt] = acc;
    }

    // ---------------- scale + mask + row max (per-q, lane-local + 2 shfl) -------------
    float mrow = -3.0e38f;
    #pragma unroll
    for (int kt = 0; kt < 16; ++kt) {
        float4 mv = *(const float4*)(mk + kt * 16 + 4 * g);   // mask[k], k = kt*16+4g+reg
        sacc[kt][0] = sacc[kt][0] * 0.125f + mv.x;
        sacc[kt][1] = sacc[kt][1] * 0.125f + mv.y;
        sacc[kt][2] = sacc[kt][2] * 0.125f + mv.z;
        sacc[kt][3] = sacc[kt][3] * 0.125f + mv.w;
        mrow = fmaxf(mrow, fmaxf(fmaxf(sacc[kt][0], sacc[kt][1]),
                                 fmaxf(sacc[kt][2], sacc[kt][3])));
    }
    mrow = fmaxf(mrow, __shfl_xor(mrow, 16));
    mrow = fmaxf(mrow, __shfl_xor(mrow, 32));

    // ---------------- exp + row sum + pack P to fp16 pairs ----------------------------
    float lsum = 0.f;
    uint32_t pk[16][2];
    #pragma unroll
    for (int kt = 0; kt < 16; ++kt) {
        float p0 = __expf(sacc[kt][0] - mrow);
        float p1 = __expf(sacc[kt][1] - mrow);
        float p2 = __expf(sacc[kt][2] - mrow);
        float p3 = __expf(sacc[kt][3] - mrow);
        lsum += (p0 + p1) + (p2 + p3);
        U32H2 u0, u1;
        u0.h[0] = (_Float16)p0; u0.h[1] = (_Float16)p1;
        u1.h[0] = (_Float16)p2; u1.h[1] = (_Float16)p3;
        pk[kt][0] = u0.u; pk[kt][1] = u1.u;
    }
    lsum += __shfl_xor(lsum, 16);
    lsum += __shfl_xor(lsum, 32);

    // ---------------- O^T = V^T * P^T  (4 d-tiles x 16q), k-chunks of 32 --------------
    f32x4 oacc[4];
    #pragma unroll
    for (int dt = 0; dt < 4; ++dt) oacc[dt] = (f32x4){0.f, 0.f, 0.f, 0.f};

    const int s0l = q | ((2 * (g & 1)) << 4);   // source lane (g' = 2*(g&1))
    const int s1l = s0l + 16;                   // source lane (g' = 2*(g&1)+1)
    const bool hiG = (g >> 1) != 0;             // which 16-tile this lane's k-slice is in

    #pragma unroll
    for (int kc = 0; kc < 8; ++kc) {
        // Build P^T B-fragment: lane needs k = kc*32 + g*8 + 0..7 for its q.
        int a0 = __shfl((int)pk[2 * kc][0], s0l);
        int a1 = __shfl((int)pk[2 * kc][1], s0l);
        int a2 = __shfl((int)pk[2 * kc][0], s1l);
        int a3 = __shfl((int)pk[2 * kc][1], s1l);
        int b0 = __shfl((int)pk[2 * kc + 1][0], s0l);
        int b1 = __shfl((int)pk[2 * kc + 1][1], s0l);
        int b2 = __shfl((int)pk[2 * kc + 1][0], s1l);
        int b3 = __shfl((int)pk[2 * kc + 1][1], s1l);
        FragU bf;
        bf.u[0] = hiG ? (uint32_t)b0 : (uint32_t)a0;
        bf.u[1] = hiG ? (uint32_t)b1 : (uint32_t)a1;
        bf.u[2] = hiG ? (uint32_t)b2 : (uint32_t)a2;
        bf.u[3] = hiG ? (uint32_t)b3 : (uint32_t)a3;
        #pragma unroll
        for (int dt = 0; dt < 4; ++dt) {
            int dr = dt * 16 + q;      // A-frag row = d index
            f16x8 av = *(const f16x8*)(&sm.s.vt[dr * 512 + (((4 * kc + g) ^ (dr & 7)) * 16)]);
            oacc[dt] = MFMA_16x16x32_F16(av, bf.v, oacc[dt], 0, 0, 0);
        }
    }

    // ---------------- normalize + stage O to LDS + coalesced global write -------------
    __syncthreads();                   // everyone done reading qn/vt before overwrite
    float inv = 1.0f / lsum;
    #pragma unroll
    for (int dt = 0; dt < 4; ++dt) {
        #pragma unroll
        for (int rg = 0; rg < 4; ++rg) {
            int d = dt * 16 + 4 * g + rg;
            sm.ostage[lq * 64 + (((d >> 2) ^ (lq & 15)) << 2) + (d & 3)] = oacc[dt][rg] * inv;
        }
    }
    __syncthreads();
    #pragma unroll
    for (int it = 0; it < 4; ++it) {
        int f = t + it * 512;          // 0..2047
        int r = f >> 4;                // local row 0..127
        int c = f & 15;
        float4 v = *(const float4*)(&sm.ostage[r * 64 + ((c ^ (r & 15)) << 2)]);
        *(float4*)(ob_g + (size_t)(half * 128 + r) * Dc + c * 4) = v;
    }
}

extern "C" void kernel_launch(void* const* d_in, const int* in_sizes, int n_in,
                              void* d_out, int out_size, void* d_ws, size_t ws_size,
                              hipStream_t stream) {
    const float* hid  = (const float*)d_in[0];
    const float* mask = (const float*)d_in[1];
    float* out = (float*)d_out;
    block_attn_kernel<<<dim3(2048), dim3(512), 0, stream>>>(hid, mask, out);
}

// Round 3
// 141.487 us; speedup vs baseline: 1.0318x; 1.0318x over previous
//
#include <hip/hip_runtime.h>
#include <hip/hip_bf16.h>
#include <stdint.h>

typedef _Float16 f16x8 __attribute__((ext_vector_type(8)));
typedef float f32x4 __attribute__((ext_vector_type(4)));

#define MFMA_16x16x32_F16 __builtin_amdgcn_mfma_f32_16x16x32_f16

constexpr int Sc = 4096, Dc = 1024, DHc = 64, CH = 256;

union U32H2 { uint32_t u; _Float16 h[2]; };
union FragU { f16x8 v; uint32_t u[4]; };

// One block = half a problem: 128 q-rows x 256 k-rows, DH=64.
// Qn LDS: [256 r][8 chunks of 8 f16], chunk' = (chunk + r) & 7.          32 KB
// Vt LDS: [64 d][32 chunks of 8 f16 along k], chunk' = (k>>3 + fd) & 31,
//         fd = (d>>2) + 2*(d&3)  (2-way max on both write & read lanes). 32 KB
// Ostage: [128 r][16 float4], chunk' = (d>>2) ^ (r&15). Union (32 KB).
__global__ __launch_bounds__(512, 4) void block_attn_kernel(
    const float* __restrict__ hid, const float* __restrict__ mask,
    float* __restrict__ out)
{
    const int bc   = blockIdx.x;
    const int half = bc & 1;
    const int p    = bc >> 1;          // 0..1023
    const int b    = p >> 8;
    const int h    = (p >> 4) & 15;
    const int sc   = p & 15;

    const float* __restrict__ qb_g = hid + ((size_t)(b * Sc + sc * CH) * Dc + h * DHc);
    float*       __restrict__ ob_g = out + ((size_t)(b * Sc + sc * CH) * Dc + h * DHc);
    const float* __restrict__ mk   = mask + b * Sc + h * CH;

    __shared__ __align__(16) union {
        struct { unsigned char qn[256 * 128]; unsigned char vt[64 * 512]; } s;
        float ostage[128 * 64];
    } sm;

    const int t = threadIdx.x;

    // ---- Stage: each thread loads a 4r x 4d fp32 micro-tile, converts to f16,
    // ---- writes Qn row-major (4x b64) and Vt transposed (4x b64). Conflict-free.
    #pragma unroll
    for (int it = 0; it < 2; ++it) {
        int f  = t + it * 512;         // 0..1023 micro-tiles
        int r4 = f >> 4;               // 0..63
        int r0 = r4 << 2;              // rows r0..r0+3
        int c  = f & 15;               // float4 col; d = 4c..4c+3
        float4 v0 = *(const float4*)(qb_g + (size_t)(r0 + 0) * Dc + c * 4);
        float4 v1 = *(const float4*)(qb_g + (size_t)(r0 + 1) * Dc + c * 4);
        float4 v2 = *(const float4*)(qb_g + (size_t)(r0 + 2) * Dc + c * 4);
        float4 v3 = *(const float4*)(qb_g + (size_t)(r0 + 3) * Dc + c * 4);
        _Float16 hv[4][4] = {
            {(_Float16)v0.x, (_Float16)v0.y, (_Float16)v0.z, (_Float16)v0.w},
            {(_Float16)v1.x, (_Float16)v1.y, (_Float16)v1.z, (_Float16)v1.w},
            {(_Float16)v2.x, (_Float16)v2.y, (_Float16)v2.z, (_Float16)v2.w},
            {(_Float16)v3.x, (_Float16)v3.y, (_Float16)v3.z, (_Float16)v3.w}};
        #pragma unroll
        for (int i = 0; i < 4; ++i) {   // Qn: row r0+i, cols 4c..4c+3
            int r = r0 + i;
            U32H2 a, bb;
            a.h[0] = hv[i][0]; a.h[1] = hv[i][1];
            bb.h[0] = hv[i][2]; bb.h[1] = hv[i][3];
            uint2 pv; pv.x = a.u; pv.y = bb.u;
            *(uint2*)(&sm.s.qn[r * 128 + ((((c >> 1) + r) & 7) * 16) + (c & 1) * 8]) = pv;
        }
        #pragma unroll
        for (int j = 0; j < 4; ++j) {   // Vt: d = 4c+j, k = r0..r0+3
            int d = 4 * c + j;
            U32H2 a, bb;
            a.h[0] = hv[0][j]; a.h[1] = hv[1][j];
            bb.h[0] = hv[2][j]; bb.h[1] = hv[3][j];
            uint2 pv; pv.x = a.u; pv.y = bb.u;
            int fd = (d >> 2) + 2 * (d & 3);   // = c + 2j
            *(uint2*)(&sm.s.vt[d * 512 + ((((r0 >> 3) + fd) & 31) * 16) + (r0 & 7) * 2]) = pv;
        }
    }
    __syncthreads();

    // ---------------- Per-wave setup ----------------
    const int wv = t >> 6;             // wave 0..7
    const int l  = t & 63;
    const int q  = l & 15;
    const int g  = l >> 4;
    const int lq = wv * 16 + q;        // local q row 0..127
    const int qrow = half * 128 + lq;  // global q row 0..255

    // Q B-fragments (col=q, k-dim=d): chunks g and g+4 of row qrow
    FragU bq0, bq1;
    bq0.v = *(const f16x8*)(&sm.s.qn[qrow * 128 + (((g + qrow) & 7) * 16)]);
    bq1.v = *(const f16x8*)(&sm.s.qn[qrow * 128 + (((g + 4 + qrow) & 7) * 16)]);

    // ---------------- S^T = K * Q^T (16 tiles of 16k x 16q) ----------------
    f32x4 sacc[16];
    #pragma unroll
    for (int kt = 0; kt < 16; ++kt) {
        int kr = kt * 16 + q;
        f16x8 a0 = *(const f16x8*)(&sm.s.qn[kr * 128 + (((g + kr) & 7) * 16)]);
        f16x8 a1 = *(const f16x8*)(&sm.s.qn[kr * 128 + (((g + 4 + kr) & 7) * 16)]);
        f32x4 acc = {0.f, 0.f, 0.f, 0.f};
        acc = MFMA_16x16x32_F16(a0, bq0.v, acc, 0, 0, 0);
        acc = MFMA_16x16x32_F16(a1, bq1.v, acc, 0, 0, 0);
        sacc[kt] = acc;
    }

    // ---------------- scale + mask + row max ----------------
    float mrow = -3.0e38f;
    #pragma unroll
    for (int kt = 0; kt < 16; ++kt) {
        float4 mv = *(const float4*)(mk + kt * 16 + 4 * g);
        sacc[kt][0] = sacc[kt][0] * 0.125f + mv.x;
        sacc[kt][1] = sacc[kt][1] * 0.125f + mv.y;
        sacc[kt][2] = sacc[kt][2] * 0.125f + mv.z;
        sacc[kt][3] = sacc[kt][3] * 0.125f + mv.w;
        mrow = fmaxf(mrow, fmaxf(fmaxf(sacc[kt][0], sacc[kt][1]),
                                 fmaxf(sacc[kt][2], sacc[kt][3])));
    }
    mrow = fmaxf(mrow, __shfl_xor(mrow, 16));
    mrow = fmaxf(mrow, __shfl_xor(mrow, 32));

    // ---------------- exp + row sum + pack P to f16 pairs ----------------
    float lsum = 0.f;
    uint32_t pk[16][2];
    #pragma unroll
    for (int kt = 0; kt < 16; ++kt) {
        float p0 = __expf(sacc[kt][0] - mrow);
        float p1 = __expf(sacc[kt][1] - mrow);
        float p2 = __expf(sacc[kt][2] - mrow);
        float p3 = __expf(sacc[kt][3] - mrow);
        lsum += (p0 + p1) + (p2 + p3);
        U32H2 u0, u1;
        u0.h[0] = (_Float16)p0; u0.h[1] = (_Float16)p1;
        u1.h[0] = (_Float16)p2; u1.h[1] = (_Float16)p3;
        pk[kt][0] = u0.u; pk[kt][1] = u1.u;
    }
    lsum += __shfl_xor(lsum, 16);
    lsum += __shfl_xor(lsum, 32);

    // ---------------- O^T = V^T * P^T (4 d-tiles, k-chunks of 32) ----------------
    f32x4 oacc[4];
    #pragma unroll
    for (int dt = 0; dt < 4; ++dt) oacc[dt] = (f32x4){0.f, 0.f, 0.f, 0.f};

    const int s0l = q | ((2 * (g & 1)) << 4);
    const int s1l = s0l + 16;
    const bool hiG = (g >> 1) != 0;

    #pragma unroll
    for (int kc = 0; kc < 8; ++kc) {
        int a0 = __shfl((int)pk[2 * kc][0], s0l);
        int a1 = __shfl((int)pk[2 * kc][1], s0l);
        int a2 = __shfl((int)pk[2 * kc][0], s1l);
        int a3 = __shfl((int)pk[2 * kc][1], s1l);
        int b0 = __shfl((int)pk[2 * kc + 1][0], s0l);
        int b1 = __shfl((int)pk[2 * kc + 1][1], s0l);
        int b2 = __shfl((int)pk[2 * kc + 1][0], s1l);
        int b3 = __shfl((int)pk[2 * kc + 1][1], s1l);
        FragU bf;
        bf.u[0] = hiG ? (uint32_t)b0 : (uint32_t)a0;
        bf.u[1] = hiG ? (uint32_t)b1 : (uint32_t)a1;
        bf.u[2] = hiG ? (uint32_t)b2 : (uint32_t)a2;
        bf.u[3] = hiG ? (uint32_t)b3 : (uint32_t)a3;
        #pragma unroll
        for (int dt = 0; dt < 4; ++dt) {
            int dr = dt * 16 + q;
            int fv = (dr >> 2) + 2 * (dr & 3);
            f16x8 av = *(const f16x8*)(&sm.s.vt[dr * 512 + (((4 * kc + g + fv) & 31) * 16)]);
            oacc[dt] = MFMA_16x16x32_F16(av, bf.v, oacc[dt], 0, 0, 0);
        }
    }

    // ---------------- normalize + stage O (float4) + coalesced write ----------------
    __syncthreads();                   // all reads of qn/vt done before overwrite
    float inv = 1.0f / lsum;
    #pragma unroll
    for (int dt = 0; dt < 4; ++dt) {
        float4 ov;
        ov.x = oacc[dt][0] * inv; ov.y = oacc[dt][1] * inv;
        ov.z = oacc[dt][2] * inv; ov.w = oacc[dt][3] * inv;
        int ch = dt * 4 + g;           // d>>2
        *(float4*)(&sm.ostage[lq * 64 + ((ch ^ (lq & 15)) << 2)]) = ov;
    }
    __syncthreads();
    #pragma unroll
    for (int it = 0; it < 4; ++it) {
        int f = t + it * 512;          // 0..2047
        int r = f >> 4;                // local row 0..127
        int c = f & 15;
        float4 v = *(const float4*)(&sm.ostage[r * 64 + ((c ^ (r & 15)) << 2)]);
        *(float4*)(ob_g + (size_t)(half * 128 + r) * Dc + c * 4) = v;
    }
}

extern "C" void kernel_launch(void* const* d_in, const int* in_sizes, int n_in,
                              void* d_out, int out_size, void* d_ws, size_t ws_size,
                              hipStream_t stream) {
    const float* hid  = (const float*)d_in[0];
    const float* mask = (const float*)d_in[1];
    float* out = (float*)d_out;
    block_attn_kernel<<<dim3(2048), dim3(512), 0, stream>>>(hid, mask, out);
}